// Round 5
// baseline (321.443 us; speedup 1.0000x reference)
//
#include <hip/hip_runtime.h>
#include <hip/hip_bf16.h>
#include <string.h>

#define N_USERS 30000
#define N_NODES 100000
#define DIM 64
#define N_EDGES 1600000
#define ROWS_PER_BUCK 256
#define NB ((N_NODES + ROWS_PER_BUCK - 1) / ROWS_PER_BUCK)   // 391 buckets
#define NGRP (NB * 64)                                       // 25024 groups of 4 rows
#define CHUNK 4096
#define NBLK_B ((N_EDGES + CHUNK - 1) / CHUNK)               // 391 blocks
#define BUCK_SLACK 2048   // per-bucket alloc slack for group-max padding
#define E_ALLOC (N_EDGES + NB * BUCK_SLACK)                  // 2,400,768 slots
#define STAGE_CAP 5120    // LDS-staged edges per bucket (mean 4092, +16 sigma)
#define GCAP 64           // max group length staged in LDS (per-row edges)

typedef __hip_bfloat16 bf16;
typedef __attribute__((ext_vector_type(8))) short short8;   // 8 bf16 = 4 VGPRs
typedef __attribute__((ext_vector_type(4))) float floatx4;  // MFMA accumulator

__device__ __forceinline__ float b2f(bf16 v) { return __bfloat162float(v); }
__device__ __forceinline__ bf16 f2b(float v) { return __float2bfloat16(v); }
__device__ __forceinline__ unsigned short fbits(float v) {
    bf16 b = f2b(v); unsigned short u; memcpy(&u, &b, 2); return u;
}
__device__ __forceinline__ float ubf(unsigned u) {
    return __uint_as_float(u << 16);
}

// dtype-flexible load/store: f32 flag selects float* vs bf16* interpretation
__device__ __forceinline__ float ld(const void* p, int i, int f32) {
    return f32 ? ((const float*)p)[i] : b2f(((const bf16*)p)[i]);
}
__device__ __forceinline__ void st(void* p, int i, float v, int f32) {
    if (f32) ((float*)p)[i] = v; else ((bf16*)p)[i] = f2b(v);
}
__device__ __forceinline__ unsigned short wbits(const void* p, int i, int f32) {
    return f32 ? fbits(((const float*)p)[i]) : ((const unsigned short*)p)[i];
}

// ---------------------------------------------------------------------------
// Detect fp32 vs bf16 per tensor (parallel: lane per element, shuffle-reduce).
// flags: 0=embeddings/out world, 1=entity, 2=vals, 3=weights
// ---------------------------------------------------------------------------
__global__ void k_detect(const void* user, const void* ent, const void* vals,
                         const void* W, int* flags, int* bsize) {
    int t = threadIdx.x;   // 128 threads
    for (int i = t; i < NB; i += 128) bsize[i] = 0;
    const void* ps[4] = { user, ent, vals, W };
    int k = t >> 5, i = t & 31;
    float v = ((const float*)ps[k])[i];
    int ok = (v == v && fabsf(v) <= 1e4f) ? 1 : 0;
    ok += __shfl_xor(ok, 1, 64);
    ok += __shfl_xor(ok, 2, 64);
    ok += __shfl_xor(ok, 4, 64);
    ok += __shfl_xor(ok, 8, 64);
    ok += __shfl_xor(ok, 16, 64);   // xor<32: reduction stays within 32-lane half
    if ((t & 31) == 0) flags[k] = (ok >= 16) ? 1 : 0;
}

// ---------------------------------------------------------------------------
// Pre-convert all weight matrices into MFMA B-fragment layout (bf16) + biases
// (fp32). One 256-thread block.
// ---------------------------------------------------------------------------
__global__ __launch_bounds__(256) void k_prepw(
    const void* W1_1, const void* b1_1, const void* W2_1, const void* b2_1,
    const void* W1_2, const void* b1_2, const void* W2_2, const void* b2_2,
    short8* wf1, float2* wsb1, short8* wf2, float* wsb2,
    const int* flags) {
    int t = threadIdx.x;
    int w = t >> 6, quad = (t >> 4) & 3, sub = t & 15;
    int fw = flags[3];
    short8 f0, f1, f2, f3;
#pragma unroll
    for (int j = 0; j < 8; ++j) {
        int k0 = quad * 8 + j, n = w * 16 + sub;
        f0[j] = (short)wbits(W1_1, k0 * 64 + n, fw);
        f1[j] = (short)wbits(W1_1, (k0 + 32) * 64 + n, fw);
        f2[j] = (short)wbits(W2_1, k0 * 64 + n, fw);
        f3[j] = (short)wbits(W2_1, (k0 + 32) * 64 + n, fw);
    }
    short8* p = wf1 + ((w * 4 + quad) * 16 + sub) * 4;
    p[0] = f0; p[1] = f1; p[2] = f2; p[3] = f3;
    if (quad == 0)
        wsb1[w * 16 + sub] = make_float2(ld(b1_1, w * 16 + sub, fw),
                                         ld(b2_1, w * 16 + sub, fw));
    int path = w >> 1, nbase = (w & 1) * 16;
    const void* W = path ? W2_2 : W1_2;
    const void* bb = path ? b2_2 : b1_2;
    short8 g0, g1;
#pragma unroll
    for (int j = 0; j < 8; ++j) {
        int k0 = quad * 8 + j, n = nbase + sub;
        g0[j] = (short)wbits(W, k0 * 32 + n, fw);
        g1[j] = (short)wbits(W, (k0 + 32) * 32 + n, fw);
    }
    short8* q = wf2 + ((w * 4 + quad) * 16 + sub) * 2;
    q[0] = g0; q[1] = g1;
    if (quad == 0) wsb2[w * 16 + sub] = ld(bb, nbase + sub, fw);
}

// ---------------------------------------------------------------------------
// Pass A: per-block LDS histogram over NB coarse buckets (bucket = row>>8).
// ---------------------------------------------------------------------------
__global__ __launch_bounds__(256) void k_hista(const int* __restrict__ rows,
                                               int* __restrict__ cnt_table,
                                               int* __restrict__ bsize) {
    __shared__ int h[NB];
    int t = threadIdx.x, blk = blockIdx.x;
    for (int b = t; b < NB; b += 256) h[b] = 0;
    __syncthreads();
    int base = blk * CHUNK + t * 4;
#pragma unroll
    for (int it = 0; it < 4; ++it) {
        int e = base + it * 1024;
        if (e < N_EDGES) {
            int4 r = *(const int4*)&rows[e];
            atomicAdd(&h[r.x >> 8], 1);
            atomicAdd(&h[r.y >> 8], 1);
            atomicAdd(&h[r.z >> 8], 1);
            atomicAdd(&h[r.w >> 8], 1);
        }
    }
    __syncthreads();
    for (int b = t; b < NB; b += 256) {
        int v = h[b];
        cnt_table[blk * NB + b] = v;           // [block][bucket], contiguous write
        if (v) atomicAdd(&bsize[b], v);
    }
}

// exclusive scan of padded bucket allocations -> bbase[0..NB]
__global__ __launch_bounds__(512) void k_bscan(const int* __restrict__ bsize,
                                               int* __restrict__ bbase) {
    __shared__ int lds[512];
    int t = threadIdx.x;
    int v = (t < NB) ? (((bsize[t] + 3) & ~3) + BUCK_SLACK) : 0;
    lds[t] = v;
    __syncthreads();
    for (int off = 1; off < 512; off <<= 1) {
        int u = (t >= off) ? lds[t - off] : 0;
        __syncthreads();
        lds[t] += u;
        __syncthreads();
    }
    if (t <= NB) bbase[t] = (t == 0) ? 0 : lds[t - 1];
}

// per-bucket scan over blocks: cnt_table[blk][b] -> bbase[b] + excl prefix
__global__ __launch_bounds__(512) void k_bscan2(int* __restrict__ cnt_table,
                                                const int* __restrict__ bbase) {
    __shared__ int lds[512];
    int t = threadIdx.x, b = blockIdx.x;
    int v = (t < NBLK_B) ? cnt_table[t * NB + b] : 0;
    lds[t] = v;
    __syncthreads();
    for (int off = 1; off < 512; off <<= 1) {
        int u = (t >= off) ? lds[t - off] : 0;
        __syncthreads();
        lds[t] += u;
        __syncthreads();
    }
    if (t < NBLK_B) cnt_table[t * NB + b] = bbase[b] + lds[t] - v;  // exclusive
}

// ---------------------------------------------------------------------------
// Pass B: stable-ish scatter into bucket order (LDS cursors, no global atomics).
// Payload: col(17b) | row-in-bucket(8b)<<17, val bits.
// ---------------------------------------------------------------------------
__global__ __launch_bounds__(256) void k_bscatter2(
    const int* __restrict__ rows, const int* __restrict__ cols,
    const void* __restrict__ vals, const int* __restrict__ cnt_table,
    int2* __restrict__ bpack, const int* __restrict__ flags) {
    __shared__ int cur[NB];
    int t = threadIdx.x, blk = blockIdx.x;
    int fv = flags[2];
    for (int b = t; b < NB; b += 256) cur[b] = cnt_table[blk * NB + b];
    __syncthreads();
    int base = blk * CHUNK + t * 4;
#pragma unroll
    for (int it = 0; it < 4; ++it) {
        int e = base + it * 1024;
        if (e < N_EDGES) {
            int4 r = *(const int4*)&rows[e];
            int4 c = *(const int4*)&cols[e];
            float v0, v1, v2, v3;
            if (fv) {
                float4 vv = *(const float4*)((const float*)vals + e);
                v0 = vv.x; v1 = vv.y; v2 = vv.z; v3 = vv.w;
            } else {
                const bf16* bp = (const bf16*)vals + e;
                v0 = b2f(bp[0]); v1 = b2f(bp[1]); v2 = b2f(bp[2]); v3 = b2f(bp[3]);
            }
            int p0 = atomicAdd(&cur[r.x >> 8], 1);
            int p1 = atomicAdd(&cur[r.y >> 8], 1);
            int p2 = atomicAdd(&cur[r.z >> 8], 1);
            int p3 = atomicAdd(&cur[r.w >> 8], 1);
            bpack[p0] = make_int2(c.x | ((r.x & 255) << 17), __float_as_int(v0));
            bpack[p1] = make_int2(c.y | ((r.y & 255) << 17), __float_as_int(v1));
            bpack[p2] = make_int2(c.z | ((r.z & 255) << 17), __float_as_int(v2));
            bpack[p3] = make_int2(c.w | ((r.w & 255) << 17), __float_as_int(v3));
        }
    }
}

// ---------------------------------------------------------------------------
// Pass C: one block per bucket. Row histogram; DEGREE-SORTED GROUPING: rank
// rows by padded count (O(256^2) broadcast compare -- all lanes read the same
// LDS word per step), form groups from consecutive ranks so group-max ~=
// group-mean (padding 22 -> ~18 edges/row). Scan -> per-group CSR
// (grp_start/grp_len) + row permutation (perm). Place edges via LDS cursors;
// epack.x holds col*128 = byte offset of the gather row (1-VALU addressing).
// ---------------------------------------------------------------------------
__global__ __launch_bounds__(256) void k_place2(
    const int* __restrict__ bsize, const int* __restrict__ bbase,
    const int2* __restrict__ bpack, int2* __restrict__ epack,
    int* __restrict__ grp_start, int* __restrict__ grp_len,
    int* __restrict__ perm) {
    __shared__ __align__(16) int2 stage[STAGE_CAP];
    __shared__ int rcnt[ROWS_PER_BUCK];     // counts, then reused as key array
    __shared__ int skey[ROWS_PER_BUCK];     // key sorted by rank
    __shared__ int scn[ROWS_PER_BUCK];      // scan workspace
    __shared__ int sbr[ROWS_PER_BUCK];      // row start by rank
    __shared__ int cur[ROWS_PER_BUCK];      // placement cursor by row
    int t = threadIdx.x, b = blockIdx.x;
    int n = bsize[b];
    int gstart = bbase[b];
    rcnt[t] = 0;
    __syncthreads();
    for (int i = t; i < n; i += 256) {
        int2 p = bpack[gstart + i];
        if (i < STAGE_CAP) stage[i] = p;
        atomicAdd(&rcnt[(p.x >> 17) & 255], 1);
    }
    __syncthreads();
    int c = rcnt[t];
    int cp = (c + 3) & ~3;                 // pad row to multiple of 4 edges
    int key = (cp << 8) | t;               // distinct keys; stable tie-break
    __syncthreads();
    rcnt[t] = key;
    __syncthreads();
    int rank = 0;
    for (int u = 0; u < 256; ++u) rank += (rcnt[u] < key) ? 1 : 0;
    skey[rank] = key;
    __syncthreads();
    // per-rank padded length = group max = cp at rank (quad | 3), ascending sort
    int gq = skey[t | 3] >> 8;             // t used as rank index here
    scn[t] = gq;
    __syncthreads();
    for (int off = 1; off < 256; off <<= 1) {
        int u = (t >= off) ? scn[t - off] : 0;
        __syncthreads();
        scn[t] += u;
        __syncthreads();
    }
    sbr[t] = gstart + scn[t] - gq;         // exclusive, indexed by rank
    __syncthreads();
    cur[t] = sbr[rank];                    // cursor for original row t
    // emit group arrays (thread t acts as rank t)
    int rowp = skey[t] & 255;
    int gid = b * 64 + (t >> 2);
    perm[gid * 4 + (t & 3)] = b * 256 + rowp;
    if ((t & 3) == 0) {
        grp_start[gid] = sbr[t];
        grp_len[gid] = skey[t | 3] >> 8;
    }
    __syncthreads();
    for (int i = t; i < n; i += 256) {
        int2 p = (i < STAGE_CAP) ? stage[i] : bpack[gstart + i];
        int r = (p.x >> 17) & 255;
        int pos = atomicAdd(&cur[r], 1);
        epack[pos] = make_int2((p.x & 0x1FFFF) << 7, p.y);  // byte offset
    }
    __syncthreads();
    int pend = sbr[rank] + (skey[rank | 3] >> 8);
    for (int pos = cur[t]; pos < pend; ++pos) epack[pos] = make_int2(0, 0);
}

// ---------------------------------------------------------------------------
// out[:, :64] = concat(user, entity); xb0 = bf16 gather table of ego0
// ---------------------------------------------------------------------------
__global__ void k_init(const void* __restrict__ user, const void* __restrict__ ent,
                       void* __restrict__ out, bf16* __restrict__ xb0,
                       const int* __restrict__ flags) {
    int i = blockIdx.x * blockDim.x + threadIdx.x;
    if (i >= N_NODES * DIM) return;
    int fo = flags[0], fe = flags[1];
    int n = i >> 6, d = i & 63;
    float v = (n < N_USERS) ? ld(user, i, fo) : ld(ent, i - N_USERS * DIM, fe);
    st(out, n * 160 + d, v, fo);
    xb0[i] = f2b(v);
}

// ---------------------------------------------------------------------------
// Gather phase: wave owns one GROUP of 4 equal-length rows (contiguous in
// CSR: row j starts at rs0 + j*emx). Edge records burst-staged into LDS;
// per-edge addressing is base + byte-offset (1 VALU). 8 edges/row/iter.
// ---------------------------------------------------------------------------
#define G8_LOAD(r) \
    int b##r = (r * emx + ei) >> 1; \
    int4 qa##r = lq4[b##r], qb##r = lq4[b##r + 1]; \
    int4 qc##r = lq4[b##r + 2], qd##r = lq4[b##r + 3];

#define G8_ISSUE(r) \
    unsigned g##r##0 = *(const unsigned short*)(xbp + (unsigned)qa##r.x); \
    unsigned g##r##1 = *(const unsigned short*)(xbp + (unsigned)qa##r.z); \
    unsigned g##r##2 = *(const unsigned short*)(xbp + (unsigned)qb##r.x); \
    unsigned g##r##3 = *(const unsigned short*)(xbp + (unsigned)qb##r.z); \
    unsigned g##r##4 = *(const unsigned short*)(xbp + (unsigned)qc##r.x); \
    unsigned g##r##5 = *(const unsigned short*)(xbp + (unsigned)qc##r.z); \
    unsigned g##r##6 = *(const unsigned short*)(xbp + (unsigned)qd##r.x); \
    unsigned g##r##7 = *(const unsigned short*)(xbp + (unsigned)qd##r.z);

#define G8_FMA(r) \
    ea##r += __int_as_float(qa##r.y) * ubf(g##r##0); \
    ea##r += __int_as_float(qa##r.w) * ubf(g##r##1); \
    ea##r += __int_as_float(qb##r.y) * ubf(g##r##2); \
    ea##r += __int_as_float(qb##r.w) * ubf(g##r##3); \
    ea##r += __int_as_float(qc##r.y) * ubf(g##r##4); \
    ea##r += __int_as_float(qc##r.w) * ubf(g##r##5); \
    ea##r += __int_as_float(qd##r.y) * ubf(g##r##6); \
    ea##r += __int_as_float(qd##r.w) * ubf(g##r##7);

#define G4_LOAD(r) \
    int tb##r = (r * emx + ei) >> 1; \
    int4 ua##r = lq4[tb##r], ub##r = lq4[tb##r + 1];

#define G4_ISSUE(r) \
    unsigned h##r##0 = *(const unsigned short*)(xbp + (unsigned)ua##r.x); \
    unsigned h##r##1 = *(const unsigned short*)(xbp + (unsigned)ua##r.z); \
    unsigned h##r##2 = *(const unsigned short*)(xbp + (unsigned)ub##r.x); \
    unsigned h##r##3 = *(const unsigned short*)(xbp + (unsigned)ub##r.z);

#define G4_FMA(r) \
    ea##r += __int_as_float(ua##r.y) * ubf(h##r##0); \
    ea##r += __int_as_float(ua##r.w) * ubf(h##r##1); \
    ea##r += __int_as_float(ub##r.y) * ubf(h##r##2); \
    ea##r += __int_as_float(ub##r.w) * ubf(h##r##3);

// overflow fallback (emx > GCAP; essentially never taken): direct global quads
#define FB_ROW_DECL(r) \
    int ej##r = (rs0 + r * emx) >> 1; \
    int4 eA##r = ep4[ej##r]; \
    int4 eB##r = ep4[ej##r + 1];

#define FB_ISSUE(r) \
    unsigned eg##r##0 = *(const unsigned short*)(xbp + (unsigned)eA##r.x); \
    unsigned eg##r##1 = *(const unsigned short*)(xbp + (unsigned)eA##r.z); \
    unsigned eg##r##2 = *(const unsigned short*)(xbp + (unsigned)eB##r.x); \
    unsigned eg##r##3 = *(const unsigned short*)(xbp + (unsigned)eB##r.z);

#define FB_ADV(r) \
    int4 nA##r = ep4[ej##r + 2]; \
    int4 nB##r = ep4[ej##r + 3]; \
    ej##r += 2;

#define FB_FMA(r) \
    ea##r += __int_as_float(eA##r.y) * ubf(eg##r##0); \
    ea##r += __int_as_float(eA##r.w) * ubf(eg##r##1); \
    ea##r += __int_as_float(eB##r.y) * ubf(eg##r##2); \
    ea##r += __int_as_float(eB##r.w) * ubf(eg##r##3); \
    eA##r = nA##r; eB##r = nB##r;

#define GATHER_BODY \
    float ea0 = 0.f, ea1 = 0.f, ea2 = 0.f, ea3 = 0.f; \
    if (emx <= GCAP) { \
        { \
            const int2* eps = (const int2*)epack + rs0; \
            int tot = emx << 2; \
            for (int i = lane; i < tot; i += 64) lq[i] = eps[i]; \
        } \
        int ei = 0; \
        for (; ei + 8 <= emx; ei += 8) { \
            G8_LOAD(0) G8_LOAD(1) G8_LOAD(2) G8_LOAD(3) \
            G8_ISSUE(0) G8_ISSUE(1) G8_ISSUE(2) G8_ISSUE(3) \
            G8_FMA(0) G8_FMA(1) G8_FMA(2) G8_FMA(3) \
        } \
        if (ei < emx) { \
            G4_LOAD(0) G4_LOAD(1) G4_LOAD(2) G4_LOAD(3) \
            G4_ISSUE(0) G4_ISSUE(1) G4_ISSUE(2) G4_ISSUE(3) \
            G4_FMA(0) G4_FMA(1) G4_FMA(2) G4_FMA(3) \
        } \
    } else { \
        const int4* ep4 = (const int4*)epack; \
        FB_ROW_DECL(0) FB_ROW_DECL(1) FB_ROW_DECL(2) FB_ROW_DECL(3) \
        for (int ei = 0; ei < emx; ei += 4) { \
            FB_ISSUE(0) FB_ISSUE(1) FB_ISSUE(2) FB_ISSUE(3) \
            FB_ADV(0) FB_ADV(1) FB_ADV(2) FB_ADV(3) \
            FB_FMA(0) FB_FMA(1) FB_FMA(2) FB_FMA(3) \
        } \
    }

// ---------------------------------------------------------------------------
// Fused layer 1 (64->64): 4 groups (16 permuted rows)/block, 4 waves. MFMA
// combine, C/D layout col=lane&15, row=(lane>>4)*4+reg. Wave w -> cols 16w..
// Rows are permuted: node of LDS row rho = perm[blockIdx*16 + rho].
// ---------------------------------------------------------------------------
__global__ __launch_bounds__(256) void k_layer1(
    const short8* __restrict__ wf1, const float2* __restrict__ wsb1,
    void* __restrict__ out, const int* __restrict__ grp_start,
    const int* __restrict__ grp_len, const int* __restrict__ perm,
    const int2* __restrict__ epack, const bf16* __restrict__ xt,
    bf16* __restrict__ xn, const int* __restrict__ flags) {
    __shared__ __align__(16) int2 lq_lds[4][4 * GCAP];
    __shared__ __align__(16) unsigned short hp_lds[16][72];
    __shared__ __align__(16) unsigned short hm_lds[16][72];
    __shared__ __align__(16) float ssq_lds[16][4];
    int t = threadIdx.x, lane = t & 63, w = t >> 6;
    int sub = lane & 15, quad = lane >> 4;
    int fo = flags[0];
    int gid = blockIdx.x * 4 + w;
    const char* xbp = (const char*)xt + (lane << 1);

    int rs0 = __builtin_amdgcn_readfirstlane(grp_start[gid]);
    int emx = __builtin_amdgcn_readfirstlane(grp_len[gid]);
    int4 pn = *(const int4*)&perm[gid * 4];
    int2* lq = lq_lds[w];
    const int4* lq4 = (const int4*)lq;
    GATHER_BODY
    {
        float s[4] = { ea0, ea1, ea2, ea3 };
        int nd[4] = { pn.x, pn.y, pn.z, pn.w };
#pragma unroll
        for (int r = 0; r < 4; ++r) {
            int node = (nd[r] < N_NODES) ? nd[r] : 0;
            float h = ld(out, node * 160 + lane, fo);
            hp_lds[w * 4 + r][lane] = fbits(h + s[r]);
            hm_lds[w * 4 + r][lane] = fbits(h * s[r]);
        }
    }
    __syncthreads();

    // A fragments: A[m=sub][k=quad*8+j] (+32 for second k-half)
    short8 Ap0 = *(const short8*)((const char*)hp_lds + sub * 144 + quad * 16);
    short8 Ap1 = *(const short8*)((const char*)hp_lds + sub * 144 + 64 + quad * 16);
    short8 Am0 = *(const short8*)((const char*)hm_lds + sub * 144 + quad * 16);
    short8 Am1 = *(const short8*)((const char*)hm_lds + sub * 144 + 64 + quad * 16);

    // B fragments: pre-converted by k_prepw (4 contiguous 16B loads + bias)
    const short8* wfp = wf1 + ((w * 4 + quad) * 16 + sub) * 4;
    short8 Bw10 = wfp[0], Bw11 = wfp[1], Bw20 = wfp[2], Bw21 = wfp[3];
    float2 bb12 = wsb1[w * 16 + sub];
    float bias1 = bb12.x, bias2 = bb12.y;
    int wbase = w * 16;

    floatx4 c1; c1[0] = bias1; c1[1] = bias1; c1[2] = bias1; c1[3] = bias1;
    floatx4 c2; c2[0] = bias2; c2[1] = bias2; c2[2] = bias2; c2[3] = bias2;
    c1 = __builtin_amdgcn_mfma_f32_16x16x32_bf16(Ap0, Bw10, c1, 0, 0, 0);
    c1 = __builtin_amdgcn_mfma_f32_16x16x32_bf16(Ap1, Bw11, c1, 0, 0, 0);
    c2 = __builtin_amdgcn_mfma_f32_16x16x32_bf16(Am0, Bw20, c2, 0, 0, 0);
    c2 = __builtin_amdgcn_mfma_f32_16x16x32_bf16(Am1, Bw21, c2, 0, 0, 0);

    float v[4], sp[4];
#pragma unroll
    for (int r = 0; r < 4; ++r) {
        float s1 = c1[r], s2 = c2[r];
        s1 = s1 > 0.f ? s1 : 0.01f * s1;
        s2 = s2 > 0.f ? s2 : 0.01f * s2;
        v[r] = s1 + s2;
        float sq = v[r] * v[r];
        sq += __shfl_xor(sq, 1, 64);
        sq += __shfl_xor(sq, 2, 64);
        sq += __shfl_xor(sq, 4, 64);
        sq += __shfl_xor(sq, 8, 64);
        sp[r] = sq;
    }
    if (sub == 0) {
#pragma unroll
        for (int r = 0; r < 4; ++r) ssq_lds[quad * 4 + r][w] = sp[r];
    }
    __syncthreads();
    const int* pblk = perm + blockIdx.x * 16;
#pragma unroll
    for (int r = 0; r < 4; ++r) {
        int row = quad * 4 + r;
        floatx4 ps = *(const floatx4*)&ssq_lds[row][0];
        float ss = ps[0] + ps[1] + ps[2] + ps[3];
        float o = v[r] * (1.0f / fmaxf(sqrtf(ss), 1e-12f));
        int n = pblk[row];
        if (n < N_NODES) {
            st(out, n * 160 + 64 + wbase + sub, o, fo);
            xn[n * 64 + wbase + sub] = f2b(o);
        }
    }
}

// ---------------------------------------------------------------------------
// Fused layer 2 (64->32): same gather; waves 0,1 = sum path (W1), waves 2,3 =
// bi path (W2); cross-path add via LDS; l2norm over 32.
// ---------------------------------------------------------------------------
__global__ __launch_bounds__(256) void k_layer2(
    const short8* __restrict__ wf2, const float* __restrict__ wsb2,
    void* __restrict__ out, const int* __restrict__ grp_start,
    const int* __restrict__ grp_len, const int* __restrict__ perm,
    const int2* __restrict__ epack, const bf16* __restrict__ xt,
    const int* __restrict__ flags) {
    __shared__ __align__(16) int2 lq_lds[4][4 * GCAP];
    __shared__ __align__(16) unsigned short hp_lds[16][72];
    __shared__ __align__(16) unsigned short hm_lds[16][72];
    __shared__ __align__(16) float bi_lds[16][32];
    __shared__ __align__(16) float ssq_lds[16][2];
    int t = threadIdx.x, lane = t & 63, w = t >> 6;
    int sub = lane & 15, quad = lane >> 4;
    int fo = flags[0];
    int gid = blockIdx.x * 4 + w;
    const char* xbp = (const char*)xt + (lane << 1);

    int rs0 = __builtin_amdgcn_readfirstlane(grp_start[gid]);
    int emx = __builtin_amdgcn_readfirstlane(grp_len[gid]);
    int4 pn = *(const int4*)&perm[gid * 4];
    int2* lq = lq_lds[w];
    const int4* lq4 = (const int4*)lq;
    GATHER_BODY
    {
        float s[4] = { ea0, ea1, ea2, ea3 };
        int nd[4] = { pn.x, pn.y, pn.z, pn.w };
#pragma unroll
        for (int r = 0; r < 4; ++r) {
            int node = (nd[r] < N_NODES) ? nd[r] : 0;
            float h = ld(out, node * 160 + 64 + lane, fo);
            hp_lds[w * 4 + r][lane] = fbits(h + s[r]);
            hm_lds[w * 4 + r][lane] = fbits(h * s[r]);
        }
    }
    __syncthreads();

    int path = w >> 1;               // 0: sum(W1), 1: bi(W2)
    int nbase = (w & 1) * 16;        // col tile within 32
    const unsigned short(*hl)[72] = path ? hm_lds : hp_lds;
    short8 Af0 = *(const short8*)((const char*)hl + sub * 144 + quad * 16);
    short8 Af1 = *(const short8*)((const char*)hl + sub * 144 + 64 + quad * 16);

    const short8* wfp = wf2 + ((w * 4 + quad) * 16 + sub) * 2;
    short8 Bf0 = wfp[0], Bf1 = wfp[1];
    float bias = wsb2[w * 16 + sub];

    floatx4 c; c[0] = bias; c[1] = bias; c[2] = bias; c[3] = bias;
    c = __builtin_amdgcn_mfma_f32_16x16x32_bf16(Af0, Bf0, c, 0, 0, 0);
    c = __builtin_amdgcn_mfma_f32_16x16x32_bf16(Af1, Bf1, c, 0, 0, 0);

    float T[4];
#pragma unroll
    for (int r = 0; r < 4; ++r) {
        float x = c[r];
        T[r] = x > 0.f ? x : 0.01f * x;
        if (path == 1) bi_lds[quad * 4 + r][nbase + sub] = T[r];
    }
    __syncthreads();

    float v[4], sp[4];
#pragma unroll
    for (int r = 0; r < 4; ++r) {
        v[r] = T[r] + bi_lds[quad * 4 + r][nbase + sub];
        float sq = v[r] * v[r];
        sq += __shfl_xor(sq, 1, 64);
        sq += __shfl_xor(sq, 2, 64);
        sq += __shfl_xor(sq, 4, 64);
        sq += __shfl_xor(sq, 8, 64);
        sp[r] = sq;
    }
    if (path == 0 && sub == 0) {
#pragma unroll
        for (int r = 0; r < 4; ++r) ssq_lds[quad * 4 + r][w & 1] = sp[r];
    }
    __syncthreads();
    if (path == 0) {
        const int* pblk = perm + blockIdx.x * 16;
#pragma unroll
        for (int r = 0; r < 4; ++r) {
            int row = quad * 4 + r;
            float ss = ssq_lds[row][0] + ssq_lds[row][1];
            float o = v[r] * (1.0f / fmaxf(sqrtf(ss), 1e-12f));
            int n = pblk[row];
            if (n < N_NODES) st(out, n * 160 + 128 + nbase + sub, o, fo);
        }
    }
}

extern "C" void kernel_launch(void* const* d_in, const int* in_sizes, int n_in,
                              void* d_out, int out_size, void* d_ws, size_t ws_size,
                              hipStream_t stream) {
    const void* user = d_in[0];
    const void* ent  = d_in[1];
    const void* vals = d_in[2];
    const void* W1_1 = d_in[3];
    const void* b1_1 = d_in[4];
    const void* W2_1 = d_in[5];
    const void* b2_1 = d_in[6];
    const void* W1_2 = d_in[7];
    const void* b1_2 = d_in[8];
    const void* W2_2 = d_in[9];
    const void* b2_2 = d_in[10];
    const int* rows  = (const int*)d_in[11];
    const int* cols  = (const int*)d_in[12];

    // ws layout: [flags][bsize][bbase][wf1][wsb1][wf2][wsb2][grp_start]
    //            [grp_len][perm][epack][xb0][xb1]
    // cnt_table aliases epack (dead before k_place2 writes epack);
    // bpack aliases xb0+xb1 (dead before k_init writes xb0).
    char* w = (char*)d_ws;
    int* flags     = (int*)w;    w += 256;
    int* bsize     = (int*)w;    w += 2048;                  // NB ints
    int* bbase     = (int*)w;    w += 2048;                  // NB+1 ints
    short8* wf1    = (short8*)w; w += 16384;                 // 1024 short8
    float2* wsb1   = (float2*)w; w += 512;
    short8* wf2    = (short8*)w; w += 8192;                  // 512 short8
    float* wsb2    = (float*)w;  w += 256;
    int* grp_start = (int*)w;    w += 100352;                // NGRP ints padded
    int* grp_len   = (int*)w;    w += 100352;
    int* perm      = (int*)w;    w += 400384;                // NGRP*4 ints
    int2* epack    = (int2*)w;   w += (size_t)E_ALLOC * 8;
    bf16* xb0      = (bf16*)w;   w += (size_t)N_NODES * DIM * 2;
    bf16* xb1      = (bf16*)w;
    int* cnt_table = (int*)epack;   // NBLK_B*NB ints = 612 KB << epack
    int2* bpack    = (int2*)xb0;    // 12.8 MB <= 25.6 MB of xb0+xb1

    k_detect<<<1, 128, 0, stream>>>(user, ent, vals, W1_1, flags, bsize);
    k_prepw<<<1, 256, 0, stream>>>(W1_1, b1_1, W2_1, b2_1, W1_2, b1_2, W2_2, b2_2,
                                   wf1, wsb1, wf2, wsb2, flags);
    k_hista<<<NBLK_B, 256, 0, stream>>>(rows, cnt_table, bsize);
    k_bscan<<<1, 512, 0, stream>>>(bsize, bbase);
    k_bscan2<<<NB, 512, 0, stream>>>(cnt_table, bbase);
    k_bscatter2<<<NBLK_B, 256, 0, stream>>>(rows, cols, vals, cnt_table, bpack, flags);
    k_place2<<<NB, 256, 0, stream>>>(bsize, bbase, bpack, epack, grp_start, grp_len, perm);
    k_init<<<(N_NODES * DIM + 255) / 256, 256, 0, stream>>>(user, ent, d_out, xb0, flags);
    k_layer1<<<NB * 16, 256, 0, stream>>>(wf1, wsb1, d_out, grp_start, grp_len, perm, epack, xb0, xb1, flags);
    k_layer2<<<NB * 16, 256, 0, stream>>>(wf2, wsb2, d_out, grp_start, grp_len, perm, epack, xb1, flags);
}

// Round 6
// 276.249 us; speedup vs baseline: 1.1636x; 1.1636x over previous
//
#include <hip/hip_runtime.h>
#include <hip/hip_bf16.h>
#include <string.h>

#define N_USERS 30000
#define N_NODES 100000
#define DIM 64
#define N_EDGES 1600000
#define ROWS_PER_BUCK 256
#define NB ((N_NODES + ROWS_PER_BUCK - 1) / ROWS_PER_BUCK)   // 391 buckets
#define NGRP (NB * 64)                                       // 25024 groups of 4 rows
#define CHUNK 8192
#define NBLK_B ((N_EDGES + CHUNK - 1) / CHUNK)               // 196 blocks
#define BUCK_SLACK 2048   // per-bucket alloc slack for group-max padding
#define E_ALLOC (N_EDGES + NB * BUCK_SLACK)                  // 2,400,768 slots
#define STAGE_CAP 5120    // LDS-staged edges per bucket (mean 4092, +16 sigma)
#define GCAP 64           // max group length staged in LDS (per-row edges)

typedef __hip_bfloat16 bf16;
typedef __attribute__((ext_vector_type(8))) short short8;   // 8 bf16 = 4 VGPRs
typedef __attribute__((ext_vector_type(4))) float floatx4;  // MFMA accumulator

__device__ __forceinline__ float b2f(bf16 v) { return __bfloat162float(v); }
__device__ __forceinline__ bf16 f2b(float v) { return __float2bfloat16(v); }
__device__ __forceinline__ unsigned short fbits(float v) {
    bf16 b = f2b(v); unsigned short u; memcpy(&u, &b, 2); return u;
}
__device__ __forceinline__ float ubf(unsigned u) {        // low bf16 of dword
    return __uint_as_float(u << 16);
}
__device__ __forceinline__ float hbf(unsigned u) {        // high bf16 of dword
    return __uint_as_float(u & 0xffff0000u);
}

// dtype-flexible load/store: f32 flag selects float* vs bf16* interpretation
__device__ __forceinline__ float ld(const void* p, int i, int f32) {
    return f32 ? ((const float*)p)[i] : b2f(((const bf16*)p)[i]);
}
__device__ __forceinline__ void st(void* p, int i, float v, int f32) {
    if (f32) ((float*)p)[i] = v; else ((bf16*)p)[i] = f2b(v);
}
__device__ __forceinline__ unsigned short wbits(const void* p, int i, int f32) {
    return f32 ? fbits(((const float*)p)[i]) : ((const unsigned short*)p)[i];
}

// ---------------------------------------------------------------------------
// Merged detect + weight-prep (one launch). Waves 0-3 detect fp32-vs-bf16 for
// {user, ent, vals, W1_1}; then all 256 threads bake MFMA B-fragments+biases.
// flags: 0=embeddings/out world, 1=entity, 2=vals, 3=weights
// ---------------------------------------------------------------------------
__global__ __launch_bounds__(256) void k_prep(
    const void* user, const void* ent, const void* vals,
    const void* W1_1, const void* b1_1, const void* W2_1, const void* b2_1,
    const void* W1_2, const void* b1_2, const void* W2_2, const void* b2_2,
    short8* wf1, float2* wsb1, short8* wf2, float* wsb2,
    int* flags, int* bsize) {
    __shared__ int lf[4];
    int t = threadIdx.x;
    for (int i = t; i < NB; i += 256) bsize[i] = 0;
    int wv = t >> 6, ln = t & 63;
    const void* ps[4] = { user, ent, vals, W1_1 };
    if (ln < 32) {
        float v = ((const float*)ps[wv])[ln];
        int ok = (v == v && fabsf(v) <= 1e4f) ? 1 : 0;
        ok += __shfl_xor(ok, 1, 64);
        ok += __shfl_xor(ok, 2, 64);
        ok += __shfl_xor(ok, 4, 64);
        ok += __shfl_xor(ok, 8, 64);
        ok += __shfl_xor(ok, 16, 64);
        if (ln == 0) { int f = (ok >= 16) ? 1 : 0; lf[wv] = f; flags[wv] = f; }
    }
    __syncthreads();
    int fw = lf[3];
    int w = t >> 6, quad = (t >> 4) & 3, sub = t & 15;
    short8 f0, f1, f2, f3;
#pragma unroll
    for (int j = 0; j < 8; ++j) {
        int k0 = quad * 8 + j, n = w * 16 + sub;
        f0[j] = (short)wbits(W1_1, k0 * 64 + n, fw);
        f1[j] = (short)wbits(W1_1, (k0 + 32) * 64 + n, fw);
        f2[j] = (short)wbits(W2_1, k0 * 64 + n, fw);
        f3[j] = (short)wbits(W2_1, (k0 + 32) * 64 + n, fw);
    }
    short8* p = wf1 + ((w * 4 + quad) * 16 + sub) * 4;
    p[0] = f0; p[1] = f1; p[2] = f2; p[3] = f3;
    if (quad == 0)
        wsb1[w * 16 + sub] = make_float2(ld(b1_1, w * 16 + sub, fw),
                                         ld(b2_1, w * 16 + sub, fw));
    int path = w >> 1, nbase = (w & 1) * 16;
    const void* W = path ? W2_2 : W1_2;
    const void* bb = path ? b2_2 : b1_2;
    short8 g0, g1;
#pragma unroll
    for (int j = 0; j < 8; ++j) {
        int k0 = quad * 8 + j, n = nbase + sub;
        g0[j] = (short)wbits(W, k0 * 32 + n, fw);
        g1[j] = (short)wbits(W, (k0 + 32) * 32 + n, fw);
    }
    short8* q = wf2 + ((w * 4 + quad) * 16 + sub) * 2;
    q[0] = g0; q[1] = g1;
    if (quad == 0) wsb2[w * 16 + sub] = ld(bb, nbase + sub, fw);
}

// ---------------------------------------------------------------------------
// Pass A: per-block LDS histogram over NB coarse buckets (bucket = row>>8).
// ---------------------------------------------------------------------------
__global__ __launch_bounds__(256) void k_hista(const int* __restrict__ rows,
                                               int* __restrict__ cnt_table,
                                               int* __restrict__ bsize) {
    __shared__ int h[NB];
    int t = threadIdx.x, blk = blockIdx.x;
    for (int b = t; b < NB; b += 256) h[b] = 0;
    __syncthreads();
    int base = blk * CHUNK + t * 4;
#pragma unroll
    for (int it = 0; it < 8; ++it) {
        int e = base + it * 1024;
        if (e < N_EDGES) {
            int4 r = *(const int4*)&rows[e];
            atomicAdd(&h[r.x >> 8], 1);
            atomicAdd(&h[r.y >> 8], 1);
            atomicAdd(&h[r.z >> 8], 1);
            atomicAdd(&h[r.w >> 8], 1);
        }
    }
    __syncthreads();
    for (int b = t; b < NB; b += 256) {
        int v = h[b];
        cnt_table[blk * NB + b] = v;           // [block][bucket], contiguous write
        if (v) atomicAdd(&bsize[b], v);
    }
}

// exclusive scan of padded bucket allocations -> bbase[0..NB]
__global__ __launch_bounds__(512) void k_bscan(const int* __restrict__ bsize,
                                               int* __restrict__ bbase) {
    __shared__ int lds[512];
    int t = threadIdx.x;
    int v = (t < NB) ? (((bsize[t] + 3) & ~3) + BUCK_SLACK) : 0;
    lds[t] = v;
    __syncthreads();
    for (int off = 1; off < 512; off <<= 1) {
        int u = (t >= off) ? lds[t - off] : 0;
        __syncthreads();
        lds[t] += u;
        __syncthreads();
    }
    if (t <= NB) bbase[t] = (t == 0) ? 0 : lds[t - 1];
}

// per-bucket scan over blocks: cnt_table[blk][b] -> bbase[b] + excl prefix
__global__ __launch_bounds__(256) void k_bscan2(int* __restrict__ cnt_table,
                                                const int* __restrict__ bbase) {
    __shared__ int lds[256];
    int t = threadIdx.x, b = blockIdx.x;
    int v = (t < NBLK_B) ? cnt_table[t * NB + b] : 0;
    lds[t] = v;
    __syncthreads();
    for (int off = 1; off < 256; off <<= 1) {
        int u = (t >= off) ? lds[t - off] : 0;
        __syncthreads();
        lds[t] += u;
        __syncthreads();
    }
    if (t < NBLK_B) cnt_table[t * NB + b] = bbase[b] + lds[t] - v;  // exclusive
}

// ---------------------------------------------------------------------------
// Pass B: stable-ish scatter into bucket order (LDS cursors, no global atomics).
// Payload: col(17b) | row-in-bucket(8b)<<17, val bits.
// ---------------------------------------------------------------------------
__global__ __launch_bounds__(256) void k_bscatter2(
    const int* __restrict__ rows, const int* __restrict__ cols,
    const void* __restrict__ vals, const int* __restrict__ cnt_table,
    int2* __restrict__ bpack, const int* __restrict__ flags) {
    __shared__ int cur[NB];
    int t = threadIdx.x, blk = blockIdx.x;
    int fv = flags[2];
    for (int b = t; b < NB; b += 256) cur[b] = cnt_table[blk * NB + b];
    __syncthreads();
    int base = blk * CHUNK + t * 4;
#pragma unroll
    for (int it = 0; it < 8; ++it) {
        int e = base + it * 1024;
        if (e < N_EDGES) {
            int4 r = *(const int4*)&rows[e];
            int4 c = *(const int4*)&cols[e];
            float v0, v1, v2, v3;
            if (fv) {
                float4 vv = *(const float4*)((const float*)vals + e);
                v0 = vv.x; v1 = vv.y; v2 = vv.z; v3 = vv.w;
            } else {
                const bf16* bp = (const bf16*)vals + e;
                v0 = b2f(bp[0]); v1 = b2f(bp[1]); v2 = b2f(bp[2]); v3 = b2f(bp[3]);
            }
            int p0 = atomicAdd(&cur[r.x >> 8], 1);
            int p1 = atomicAdd(&cur[r.y >> 8], 1);
            int p2 = atomicAdd(&cur[r.z >> 8], 1);
            int p3 = atomicAdd(&cur[r.w >> 8], 1);
            bpack[p0] = make_int2(c.x | ((r.x & 255) << 17), __float_as_int(v0));
            bpack[p1] = make_int2(c.y | ((r.y & 255) << 17), __float_as_int(v1));
            bpack[p2] = make_int2(c.z | ((r.z & 255) << 17), __float_as_int(v2));
            bpack[p3] = make_int2(c.w | ((r.w & 255) << 17), __float_as_int(v3));
        }
    }
}

// ---------------------------------------------------------------------------
// Pass C: one block per bucket. Row histogram; degree-sorted grouping (rank
// rows by padded count; consecutive ranks form groups of 4 -> group-max ~=
// group-mean). Scan -> per-group CSR (grp_start/grp_len) + row permutation.
// Place edges via LDS cursors; epack.x holds col*128 byte offset.
// ---------------------------------------------------------------------------
__global__ __launch_bounds__(256) void k_place2(
    const int* __restrict__ bsize, const int* __restrict__ bbase,
    const int2* __restrict__ bpack, int2* __restrict__ epack,
    int* __restrict__ grp_start, int* __restrict__ grp_len,
    int* __restrict__ perm) {
    __shared__ __align__(16) int2 stage[STAGE_CAP];
    __shared__ int rcnt[ROWS_PER_BUCK];     // counts, then reused as key array
    __shared__ int skey[ROWS_PER_BUCK];     // key sorted by rank
    __shared__ int scn[ROWS_PER_BUCK];      // scan workspace
    __shared__ int sbr[ROWS_PER_BUCK];      // row start by rank
    __shared__ int cur[ROWS_PER_BUCK];      // placement cursor by row
    int t = threadIdx.x, b = blockIdx.x;
    int n = bsize[b];
    int gstart = bbase[b];
    rcnt[t] = 0;
    __syncthreads();
    for (int i = t; i < n; i += 256) {
        int2 p = bpack[gstart + i];
        if (i < STAGE_CAP) stage[i] = p;
        atomicAdd(&rcnt[(p.x >> 17) & 255], 1);
    }
    __syncthreads();
    int c = rcnt[t];
    int cp = (c + 3) & ~3;                 // pad row to multiple of 4 edges
    int key = (cp << 8) | t;               // distinct keys; stable tie-break
    __syncthreads();
    rcnt[t] = key;
    __syncthreads();
    int rank = 0;
    for (int u = 0; u < 256; ++u) rank += (rcnt[u] < key) ? 1 : 0;
    skey[rank] = key;
    __syncthreads();
    int gq = skey[t | 3] >> 8;             // group (of 4 consecutive ranks) max
    scn[t] = gq;
    __syncthreads();
    for (int off = 1; off < 256; off <<= 1) {
        int u = (t >= off) ? scn[t - off] : 0;
        __syncthreads();
        scn[t] += u;
        __syncthreads();
    }
    sbr[t] = gstart + scn[t] - gq;         // exclusive, indexed by rank
    __syncthreads();
    cur[t] = sbr[rank];                    // cursor for original row t
    int rowp = skey[t] & 255;
    int gid = b * 64 + (t >> 2);
    perm[gid * 4 + (t & 3)] = b * 256 + rowp;
    if ((t & 3) == 0) {
        grp_start[gid] = sbr[t];
        grp_len[gid] = skey[t | 3] >> 8;
    }
    __syncthreads();
    for (int i = t; i < n; i += 256) {
        int2 p = (i < STAGE_CAP) ? stage[i] : bpack[gstart + i];
        int r = (p.x >> 17) & 255;
        int pos = atomicAdd(&cur[r], 1);
        epack[pos] = make_int2((p.x & 0x1FFFF) << 7, p.y);  // byte offset
    }
    __syncthreads();
    int pend = sbr[rank] + (skey[rank | 3] >> 8);
    for (int pos = cur[t]; pos < pend; ++pos) epack[pos] = make_int2(0, 0);
}

// ---------------------------------------------------------------------------
// out[:, :64] = concat(user, entity); xb0 = bf16 gather table of ego0
// ---------------------------------------------------------------------------
__global__ void k_init(const void* __restrict__ user, const void* __restrict__ ent,
                       void* __restrict__ out, bf16* __restrict__ xb0,
                       const int* __restrict__ flags) {
    int i = blockIdx.x * blockDim.x + threadIdx.x;
    if (i >= N_NODES * DIM) return;
    int fo = flags[0], fe = flags[1];
    int n = i >> 6, d = i & 63;
    float v = (n < N_USERS) ? ld(user, i, fo) : ld(ent, i - N_USERS * DIM, fe);
    st(out, n * 160 + d, v, fo);
    xb0[i] = f2b(v);
}

// ---------------------------------------------------------------------------
// PAIR-GATHER: one wave64 VMEM instruction covers TWO edges. Lane loads a
// dword (2 bf16 dims); lanes 0-31 = edge e, lanes 32-63 = edge e+1 (each half
// reads its own int2 edge record from LDS via lqh = lq + (lane>>5) -- no
// cndmasks). Accumulator = float2 per row (dims 2*(lane&31), +1). Cross-half
// combine = one shfl_xor(32) per component. Halves VMEM instruction count.
// ---------------------------------------------------------------------------
#define GP_LOAD8(r) \
    int2 pa##r = lqh[r * emx + ei],     pb##r = lqh[r * emx + ei + 2], \
         pc##r = lqh[r * emx + ei + 4], pd##r = lqh[r * emx + ei + 6];

#define GP_ISSUE8(r) \
    unsigned ga##r = *(const unsigned*)(xp + (unsigned)pa##r.x); \
    unsigned gb##r = *(const unsigned*)(xp + (unsigned)pb##r.x); \
    unsigned gc##r = *(const unsigned*)(xp + (unsigned)pc##r.x); \
    unsigned gd##r = *(const unsigned*)(xp + (unsigned)pd##r.x);

#define GP_FMA8(r) \
    { float va = __int_as_float(pa##r.y), vb = __int_as_float(pb##r.y); \
      float vc = __int_as_float(pc##r.y), vd = __int_as_float(pd##r.y); \
      ax##r += va * ubf(ga##r); ay##r += va * hbf(ga##r); \
      ax##r += vb * ubf(gb##r); ay##r += vb * hbf(gb##r); \
      ax##r += vc * ubf(gc##r); ay##r += vc * hbf(gc##r); \
      ax##r += vd * ubf(gd##r); ay##r += vd * hbf(gd##r); }

#define GP_LOAD4(r) \
    int2 ta##r = lqh[r * emx + ei], tb##r = lqh[r * emx + ei + 2];

#define GP_ISSUE4(r) \
    unsigned ha##r = *(const unsigned*)(xp + (unsigned)ta##r.x); \
    unsigned hb##r = *(const unsigned*)(xp + (unsigned)tb##r.x);

#define GP_FMA4(r) \
    { float va = __int_as_float(ta##r.y), vb = __int_as_float(tb##r.y); \
      ax##r += va * ubf(ha##r); ay##r += va * hbf(ha##r); \
      ax##r += vb * ubf(hb##r); ay##r += vb * hbf(hb##r); }

// overflow fallback (emx > GCAP; ~never taken): per-lane-dim ushort gather,
// then redistribute into the pair layout via two bpermutes per row.
#define FB_ROW(r) { \
    float s_ = 0.f; \
    const int2* eb = (const int2*)epack + rs0 + r * emx; \
    for (int e = 0; e < emx; e += 2) { \
        int4 q = *(const int4*)(eb + e); \
        s_ += __int_as_float(q.y) * b2f(*(const bf16*)(xq + (unsigned)q.x)); \
        s_ += __int_as_float(q.w) * b2f(*(const bf16*)(xq + (unsigned)q.z)); \
    } \
    ax##r = __shfl(s_, (lane & 31) << 1, 64); \
    ay##r = __shfl(s_, ((lane & 31) << 1) | 1, 64); }

#define GATHER_BODY \
    float ax0 = 0.f, ay0 = 0.f, ax1 = 0.f, ay1 = 0.f; \
    float ax2 = 0.f, ay2 = 0.f, ax3 = 0.f, ay3 = 0.f; \
    if (emx <= GCAP) { \
        { const int2* eps = (const int2*)epack + rs0; \
          int tot = emx << 2; \
          for (int i = lane; i < tot; i += 64) lq[i] = eps[i]; } \
        int ei = 0; \
        for (; ei + 8 <= emx; ei += 8) { \
            GP_LOAD8(0) GP_LOAD8(1) GP_LOAD8(2) GP_LOAD8(3) \
            GP_ISSUE8(0) GP_ISSUE8(1) GP_ISSUE8(2) GP_ISSUE8(3) \
            GP_FMA8(0) GP_FMA8(1) GP_FMA8(2) GP_FMA8(3) \
        } \
        if (ei < emx) { \
            GP_LOAD4(0) GP_LOAD4(1) GP_LOAD4(2) GP_LOAD4(3) \
            GP_ISSUE4(0) GP_ISSUE4(1) GP_ISSUE4(2) GP_ISSUE4(3) \
            GP_FMA4(0) GP_FMA4(1) GP_FMA4(2) GP_FMA4(3) \
        } \
        ax0 += __shfl_xor(ax0, 32, 64); ay0 += __shfl_xor(ay0, 32, 64); \
        ax1 += __shfl_xor(ax1, 32, 64); ay1 += __shfl_xor(ay1, 32, 64); \
        ax2 += __shfl_xor(ax2, 32, 64); ay2 += __shfl_xor(ay2, 32, 64); \
        ax3 += __shfl_xor(ax3, 32, 64); ay3 += __shfl_xor(ay3, 32, 64); \
    } else { \
        const char* xq = (const char*)xt + (lane << 1); \
        FB_ROW(0) FB_ROW(1) FB_ROW(2) FB_ROW(3) \
    }

// Staging: lanes of half h write rows {2h, 2h+1}; h is read from the bf16
// gather table (L2-hot; replaces cold fp32 out reads); packed uint LDS write.
#define STAGE_HPHM \
    { int half = lane >> 5, li = lane & 31; \
      unsigned* hp32 = (unsigned*)hp_lds; \
      unsigned* hm32 = (unsigned*)hm_lds; \
      _Pragma("unroll") \
      for (int k = 0; k < 2; ++k) { \
          float sx = half ? (k ? ax3 : ax2) : (k ? ax1 : ax0); \
          float sy = half ? (k ? ay3 : ay2) : (k ? ay1 : ay0); \
          int node = half ? (k ? pn.w : pn.z) : (k ? pn.y : pn.x); \
          node = (node < N_NODES) ? node : 0; \
          unsigned hg = *(const unsigned*)((const char*)xt + node * 128 + (li << 2)); \
          float h0 = ubf(hg), h1 = hbf(hg); \
          int row = w * 4 + ((half << 1) | k); \
          hp32[row * 36 + li] = (unsigned)fbits(h0 + sx) | ((unsigned)fbits(h1 + sy) << 16); \
          hm32[row * 36 + li] = (unsigned)fbits(h0 * sx) | ((unsigned)fbits(h1 * sy) << 16); \
      } }

// ---------------------------------------------------------------------------
// Fused layer 1 (64->64): 4 groups (16 permuted rows)/block, 4 waves. MFMA
// combine, C/D layout col=lane&15, row=(lane>>4)*4+reg. Wave w -> cols 16w..
// ---------------------------------------------------------------------------
__global__ __launch_bounds__(256) void k_layer1(
    const short8* __restrict__ wf1, const float2* __restrict__ wsb1,
    void* __restrict__ out, const int* __restrict__ grp_start,
    const int* __restrict__ grp_len, const int* __restrict__ perm,
    const int2* __restrict__ epack, const bf16* __restrict__ xt,
    bf16* __restrict__ xn, const int* __restrict__ flags) {
    __shared__ __align__(16) int2 lq_lds[4][4 * GCAP];
    __shared__ __align__(16) unsigned short hp_lds[16][72];
    __shared__ __align__(16) unsigned short hm_lds[16][72];
    __shared__ __align__(16) float ssq_lds[16][4];
    int t = threadIdx.x, lane = t & 63, w = t >> 6;
    int sub = lane & 15, quad = lane >> 4;
    int fo = flags[0];
    int gid = blockIdx.x * 4 + w;
    const char* xp = (const char*)xt + ((lane & 31) << 2);

    int rs0 = __builtin_amdgcn_readfirstlane(grp_start[gid]);
    int emx = __builtin_amdgcn_readfirstlane(grp_len[gid]);
    int4 pn = *(const int4*)&perm[gid * 4];
    int2* lq = lq_lds[w];
    const int2* lqh = lq + (lane >> 5);
    GATHER_BODY
    STAGE_HPHM
    __syncthreads();

    // A fragments: A[m=sub][k=quad*8+j] (+32 for second k-half)
    short8 Ap0 = *(const short8*)((const char*)hp_lds + sub * 144 + quad * 16);
    short8 Ap1 = *(const short8*)((const char*)hp_lds + sub * 144 + 64 + quad * 16);
    short8 Am0 = *(const short8*)((const char*)hm_lds + sub * 144 + quad * 16);
    short8 Am1 = *(const short8*)((const char*)hm_lds + sub * 144 + 64 + quad * 16);

    // B fragments: pre-converted by k_prep (4 contiguous 16B loads + bias)
    const short8* wfp = wf1 + ((w * 4 + quad) * 16 + sub) * 4;
    short8 Bw10 = wfp[0], Bw11 = wfp[1], Bw20 = wfp[2], Bw21 = wfp[3];
    float2 bb12 = wsb1[w * 16 + sub];
    float bias1 = bb12.x, bias2 = bb12.y;
    int wbase = w * 16;

    floatx4 c1; c1[0] = bias1; c1[1] = bias1; c1[2] = bias1; c1[3] = bias1;
    floatx4 c2; c2[0] = bias2; c2[1] = bias2; c2[2] = bias2; c2[3] = bias2;
    c1 = __builtin_amdgcn_mfma_f32_16x16x32_bf16(Ap0, Bw10, c1, 0, 0, 0);
    c1 = __builtin_amdgcn_mfma_f32_16x16x32_bf16(Ap1, Bw11, c1, 0, 0, 0);
    c2 = __builtin_amdgcn_mfma_f32_16x16x32_bf16(Am0, Bw20, c2, 0, 0, 0);
    c2 = __builtin_amdgcn_mfma_f32_16x16x32_bf16(Am1, Bw21, c2, 0, 0, 0);

    float v[4], sp[4];
#pragma unroll
    for (int r = 0; r < 4; ++r) {
        float s1 = c1[r], s2 = c2[r];
        s1 = s1 > 0.f ? s1 : 0.01f * s1;
        s2 = s2 > 0.f ? s2 : 0.01f * s2;
        v[r] = s1 + s2;
        float sq = v[r] * v[r];
        sq += __shfl_xor(sq, 1, 64);
        sq += __shfl_xor(sq, 2, 64);
        sq += __shfl_xor(sq, 4, 64);
        sq += __shfl_xor(sq, 8, 64);
        sp[r] = sq;
    }
    if (sub == 0) {
#pragma unroll
        for (int r = 0; r < 4; ++r) ssq_lds[quad * 4 + r][w] = sp[r];
    }
    __syncthreads();
    const int* pblk = perm + blockIdx.x * 16;
#pragma unroll
    for (int r = 0; r < 4; ++r) {
        int row = quad * 4 + r;
        floatx4 ps = *(const floatx4*)&ssq_lds[row][0];
        float ss = ps[0] + ps[1] + ps[2] + ps[3];
        float o = v[r] * (1.0f / fmaxf(sqrtf(ss), 1e-12f));
        int n = pblk[row];
        if (n < N_NODES) {
            st(out, n * 160 + 64 + wbase + sub, o, fo);
            xn[n * 64 + wbase + sub] = f2b(o);
        }
    }
}

// ---------------------------------------------------------------------------
// Fused layer 2 (64->32): same gather; waves 0,1 = sum path (W1), waves 2,3 =
// bi path (W2); cross-path add via LDS; l2norm over 32.
// ---------------------------------------------------------------------------
__global__ __launch_bounds__(256) void k_layer2(
    const short8* __restrict__ wf2, const float* __restrict__ wsb2,
    void* __restrict__ out, const int* __restrict__ grp_start,
    const int* __restrict__ grp_len, const int* __restrict__ perm,
    const int2* __restrict__ epack, const bf16* __restrict__ xt,
    const int* __restrict__ flags) {
    __shared__ __align__(16) int2 lq_lds[4][4 * GCAP];
    __shared__ __align__(16) unsigned short hp_lds[16][72];
    __shared__ __align__(16) unsigned short hm_lds[16][72];
    __shared__ __align__(16) float bi_lds[16][32];
    __shared__ __align__(16) float ssq_lds[16][2];
    int t = threadIdx.x, lane = t & 63, w = t >> 6;
    int sub = lane & 15, quad = lane >> 4;
    int fo = flags[0];
    int gid = blockIdx.x * 4 + w;
    const char* xp = (const char*)xt + ((lane & 31) << 2);

    int rs0 = __builtin_amdgcn_readfirstlane(grp_start[gid]);
    int emx = __builtin_amdgcn_readfirstlane(grp_len[gid]);
    int4 pn = *(const int4*)&perm[gid * 4];
    int2* lq = lq_lds[w];
    const int2* lqh = lq + (lane >> 5);
    GATHER_BODY
    STAGE_HPHM
    __syncthreads();

    int path = w >> 1;               // 0: sum(W1), 1: bi(W2)
    int nbase = (w & 1) * 16;        // col tile within 32
    const unsigned short(*hl)[72] = path ? hm_lds : hp_lds;
    short8 Af0 = *(const short8*)((const char*)hl + sub * 144 + quad * 16);
    short8 Af1 = *(const short8*)((const char*)hl + sub * 144 + 64 + quad * 16);

    const short8* wfp = wf2 + ((w * 4 + quad) * 16 + sub) * 2;
    short8 Bf0 = wfp[0], Bf1 = wfp[1];
    float bias = wsb2[w * 16 + sub];

    floatx4 c; c[0] = bias; c[1] = bias; c[2] = bias; c[3] = bias;
    c = __builtin_amdgcn_mfma_f32_16x16x32_bf16(Af0, Bf0, c, 0, 0, 0);
    c = __builtin_amdgcn_mfma_f32_16x16x32_bf16(Af1, Bf1, c, 0, 0, 0);

    float T[4];
#pragma unroll
    for (int r = 0; r < 4; ++r) {
        float x = c[r];
        T[r] = x > 0.f ? x : 0.01f * x;
        if (path == 1) bi_lds[quad * 4 + r][nbase + sub] = T[r];
    }
    __syncthreads();

    float v[4], sp[4];
#pragma unroll
    for (int r = 0; r < 4; ++r) {
        v[r] = T[r] + bi_lds[quad * 4 + r][nbase + sub];
        float sq = v[r] * v[r];
        sq += __shfl_xor(sq, 1, 64);
        sq += __shfl_xor(sq, 2, 64);
        sq += __shfl_xor(sq, 4, 64);
        sq += __shfl_xor(sq, 8, 64);
        sp[r] = sq;
    }
    if (path == 0 && sub == 0) {
#pragma unroll
        for (int r = 0; r < 4; ++r) ssq_lds[quad * 4 + r][w & 1] = sp[r];
    }
    __syncthreads();
    if (path == 0) {
        const int* pblk = perm + blockIdx.x * 16;
#pragma unroll
        for (int r = 0; r < 4; ++r) {
            int row = quad * 4 + r;
            float ss = ssq_lds[row][0] + ssq_lds[row][1];
            float o = v[r] * (1.0f / fmaxf(sqrtf(ss), 1e-12f));
            int n = pblk[row];
            if (n < N_NODES) st(out, n * 160 + 128 + nbase + sub, o, fo);
        }
    }
}

extern "C" void kernel_launch(void* const* d_in, const int* in_sizes, int n_in,
                              void* d_out, int out_size, void* d_ws, size_t ws_size,
                              hipStream_t stream) {
    const void* user = d_in[0];
    const void* ent  = d_in[1];
    const void* vals = d_in[2];
    const void* W1_1 = d_in[3];
    const void* b1_1 = d_in[4];
    const void* W2_1 = d_in[5];
    const void* b2_1 = d_in[6];
    const void* W1_2 = d_in[7];
    const void* b1_2 = d_in[8];
    const void* W2_2 = d_in[9];
    const void* b2_2 = d_in[10];
    const int* rows  = (const int*)d_in[11];
    const int* cols  = (const int*)d_in[12];

    // ws layout: [flags][bsize][bbase][wf1][wsb1][wf2][wsb2][grp_start]
    //            [grp_len][perm][epack][xb0][xb1]
    // cnt_table aliases epack (dead before k_place2 writes epack);
    // bpack aliases xb0+xb1 (dead before k_init writes xb0).
    char* w = (char*)d_ws;
    int* flags     = (int*)w;    w += 256;
    int* bsize     = (int*)w;    w += 2048;                  // NB ints
    int* bbase     = (int*)w;    w += 2048;                  // NB+1 ints
    short8* wf1    = (short8*)w; w += 16384;                 // 1024 short8
    float2* wsb1   = (float2*)w; w += 512;
    short8* wf2    = (short8*)w; w += 8192;                  // 512 short8
    float* wsb2    = (float*)w;  w += 256;
    int* grp_start = (int*)w;    w += 100352;                // NGRP ints padded
    int* grp_len   = (int*)w;    w += 100352;
    int* perm      = (int*)w;    w += 400384;                // NGRP*4 ints
    int2* epack    = (int2*)w;   w += (size_t)E_ALLOC * 8;
    bf16* xb0      = (bf16*)w;   w += (size_t)N_NODES * DIM * 2;
    bf16* xb1      = (bf16*)w;
    int* cnt_table = (int*)epack;   // NBLK_B*NB ints = 307 KB << epack
    int2* bpack    = (int2*)xb0;    // 12.8 MB <= 25.6 MB of xb0+xb1

    k_prep<<<1, 256, 0, stream>>>(user, ent, vals, W1_1, b1_1, W2_1, b2_1,
                                  W1_2, b1_2, W2_2, b2_2,
                                  wf1, wsb1, wf2, wsb2, flags, bsize);
    k_hista<<<NBLK_B, 256, 0, stream>>>(rows, cnt_table, bsize);
    k_bscan<<<1, 512, 0, stream>>>(bsize, bbase);
    k_bscan2<<<NB, 256, 0, stream>>>(cnt_table, bbase);
    k_bscatter2<<<NBLK_B, 256, 0, stream>>>(rows, cols, vals, cnt_table, bpack, flags);
    k_place2<<<NB, 256, 0, stream>>>(bsize, bbase, bpack, epack, grp_start, grp_len, perm);
    k_init<<<(N_NODES * DIM + 255) / 256, 256, 0, stream>>>(user, ent, d_out, xb0, flags);
    k_layer1<<<NB * 16, 256, 0, stream>>>(wf1, wsb1, d_out, grp_start, grp_len, perm, epack, xb0, xb1, flags);
    k_layer2<<<NB * 16, 256, 0, stream>>>(wf2, wsb2, d_out, grp_start, grp_len, perm, epack, xb1, flags);
}